// Round 10
// baseline (244.639 us; speedup 1.0000x reference)
//
#include <hip/hip_runtime.h>
#include <stdint.h>

#define HW 16384
#define NI 64
#define NM 256
#define WORDS 256

// ws layout (~3 MB used)
#define OFF_STATE  0u            // 1 MB state bytes (iter 0)
#define OFF_STATE2 (1u << 20)    // 1 MB state bytes (iter 5 handoff)
#define OFF_PACKED (2u << 20)    // 512 KB bit-packed masks [word][mask]
#define OFF_DIOUT  0x280000u     // 256 KB diou transposed diouT[col][row]
#define OFF_COMPM  0x2C0000u
#define OFF_CNT    0x2C1000u     // 64 counters + done ticket at [64]

// ---------------- setup: state init + mask pack + counter zero (proven) -----
__global__ __launch_bounds__(256) void setup_kernel(
    const float* __restrict__ seg, const float* __restrict__ x,
    const float* __restrict__ targets, unsigned char* __restrict__ state,
    unsigned long long* __restrict__ packed, int* __restrict__ counters) {
    #pragma clang fp contract(off)
    const int gid = blockIdx.x * 256 + threadIdx.x;
    for (int u = gid; u < 262144; u += 131072) {
        const int px0 = u * 4;
        const float4 xv = *(const float4*)(x + px0);
        const float4 tv = *(const float4*)(targets + px0);
        float xs[4] = {xv.x, xv.y, xv.z, xv.w};
        float ts[4] = {tv.x, tv.y, tv.z, tv.w};
        uint32_t st = 0;
        for (int j = 0; j < 4; ++j) {
            float xt = xs[j] * ts[j];
            int b1 = (xt > 0.5f) ? 1 : 0;
            int tb = (ts[j] > 0.5f) ? 1 : 0;
            st |= (uint32_t)(b1 | ((b1 ^ 1) << 1) | (tb << 2)) << (8 * j);
        }
        *(uint32_t*)(state + px0) = st;
    }
    const int wv = gid >> 6, lane = gid & 63;
    for (int t = 0; t < 32; ++t) {
        int gwi = wv * 32 + t;
        int i = gwi >> 8, w = gwi & 255;
        float v = seg[(size_t)i * HW + w * 64 + lane];
        unsigned long long m = __ballot(v > 0.5f);
        if (lane == 0) packed[w * NM + i] = m;
    }
    if (gid < NI + 1) counters[gid] = 0;
}

// ---------------- fused diou + compm (proven) -------------------------------
__global__ __launch_bounds__(256) void diou_compm_kernel(
    const unsigned long long* __restrict__ packed, const int* __restrict__ labels,
    float* __restrict__ diouT, float* __restrict__ compm) {
    #pragma clang fp contract(off)
    __shared__ unsigned long long colj[WORDS];
    __shared__ float red[NM];
    const int j = blockIdx.x, i = threadIdx.x;
    colj[i] = packed[i * NM + j];
    __syncthreads();
    int inter = 0, si = 0, sj = 0;
    for (int w = 0; w < WORDS; ++w) {
        unsigned long long a = colj[w];
        unsigned long long b = packed[w * NM + i];
        inter += __popcll(a & b);
        sj += __popcll(a);
        si += __popcll(b);
    }
    float d = 0.0f;
    if (j > i && labels[i] == labels[j]) {
        float u = (float)(si + sj - inter);
        d = (float)inter / u;
    }
    diouT[j * NM + i] = d;
    red[i] = d;
    __syncthreads();
    for (int off = 128; off > 0; off >>= 1) {
        if (i < off) red[i] = fmaxf(red[i], red[i + off]);
        __syncthreads();
    }
    if (i == 0) {
        float m = red[0];
        float t = m * m;
        compm[j] = expf(-2.0f * t);
    }
}

// ---------------- CRF: 5 iters/launch, fm in LDS, kw in VGPRs ---------------
// 1024 blocks = 64 img x 16 tiles of 8 rows; 576 threads = 18-row window x 32
// quads (1 thread : 1 state word). fm = feat+10 staged to LDS (coalesced);
// each thread computes its 36 kw values ONCE into registers (exact reference
// formula; center tap -> expf(-0.0f)=1 -> 3.0f; OOB taps -> kw=0 exactly,
// proven underflow). Sweep s computes rows [max(0,r0-4+s), min(128,r0+12-s)) —
// taps always inside the prior sweep's computed range (proven halo argument).
// launch_bounds(576,4): VGPR cap 128 — room for kw[9][4] resident.
template <bool FIRST>
__global__ __launch_bounds__(576, 4) void crf5_kernel(
    const float* __restrict__ feat, const float* __restrict__ scores,
    const float* __restrict__ diouT, const float* __restrict__ compm,
    const unsigned char* __restrict__ gsrc, unsigned char* __restrict__ gdst2,
    float* __restrict__ out, int* __restrict__ counters) {
    #pragma clang fp contract(off)
    __shared__ float fmL[3][18 * 128];    // 27648 B
    __shared__ uint32_t stw[2][18 * 32];  // 4608 B  (total 32256 B)
    const int tid = threadIdx.x, bid = blockIdx.x;
    const int img = bid >> 4, r0 = (bid & 15) * 8;
    const int w0 = r0 - 5;
    const int rel = tid >> 5;             // 0..17
    const int xc = (tid & 31) * 4;
    const int y = w0 + rel;

    // ---- coef (phase A, blocks 0..255) — fmL as scratch --------------------
    if (FIRST && bid < NM) {
        float* red = &fmL[0][0];
        if (tid < NM) {
            float d = diouT[bid * NM + tid];
            float dd = d * d;
            float dec = expf(-2.0f * dd);
            red[tid] = dec / compm[tid];
        }
        __syncthreads();
        for (int off = 128; off > 0; off >>= 1) {
            if (tid < off) red[tid] = fminf(red[tid], red[tid + off]);
            __syncthreads();
        }
        if (tid == 0) out[bid] = scores[bid] * red[0];
        __syncthreads();
    }

    // ---- stage fm = feat + 10 (coalesced) + window state -------------------
    if ((unsigned)y < 128u) {
        const float* fb = feat + (size_t)img * 3 * HW + y * 128 + xc;
        #pragma unroll
        for (int ch = 0; ch < 3; ++ch) {
            float4 v = *(const float4*)(fb + ch * HW);
            *(float4*)&fmL[ch][rel * 128 + xc] =
                make_float4(v.x + 10.0f, v.y + 10.0f, v.z + 10.0f, v.w + 10.0f);
        }
        stw[0][tid] = ((const uint32_t*)(gsrc + (size_t)img * HW + y * 128))[tid & 31];
    }
    __syncthreads();

    // ---- kw[9][4] into registers (once; reused by all 5 sweeps) ------------
    const bool compute = ((unsigned)y < 128u) && (y >= r0 - 4) && (y < r0 + 12);
    float kw[9][4];
    if (compute) {
        float c0[4], c1[4], c2[4];
        {
            float4 a = *(const float4*)&fmL[0][rel * 128 + xc];
            c0[0] = a.x; c0[1] = a.y; c0[2] = a.z; c0[3] = a.w;
            a = *(const float4*)&fmL[1][rel * 128 + xc];
            c1[0] = a.x; c1[1] = a.y; c1[2] = a.z; c1[3] = a.w;
            a = *(const float4*)&fmL[2][rel * 128 + xc];
            c2[0] = a.x; c2[1] = a.y; c2[2] = a.z; c2[3] = a.w;
        }
        #pragma unroll
        for (int g = 0; g < 3; ++g) {
            const int dy = g - 1;
            const int ny = y + dy;
            if ((unsigned)ny < 128u) {
                const int rr = (rel + dy) * 128;
                float rv0[6], rv1[6], rv2[6];
                {
                    float4 m = *(const float4*)&fmL[0][rr + xc];
                    rv0[1] = m.x; rv0[2] = m.y; rv0[3] = m.z; rv0[4] = m.w;
                    rv0[0] = (xc > 0) ? fmL[0][rr + xc - 1] : 0.0f;
                    rv0[5] = (xc < 124) ? fmL[0][rr + xc + 4] : 0.0f;
                    m = *(const float4*)&fmL[1][rr + xc];
                    rv1[1] = m.x; rv1[2] = m.y; rv1[3] = m.z; rv1[4] = m.w;
                    rv1[0] = (xc > 0) ? fmL[1][rr + xc - 1] : 0.0f;
                    rv1[5] = (xc < 124) ? fmL[1][rr + xc + 4] : 0.0f;
                    m = *(const float4*)&fmL[2][rr + xc];
                    rv2[1] = m.x; rv2[2] = m.y; rv2[3] = m.z; rv2[4] = m.w;
                    rv2[0] = (xc > 0) ? fmL[2][rr + xc - 1] : 0.0f;
                    rv2[5] = (xc < 124) ? fmL[2][rr + xc + 4] : 0.0f;
                }
                #pragma unroll
                for (int dxi = 0; dxi < 3; ++dxi) {
                    const int dx = dxi - 1, k = g * 3 + dxi;
                    const float sp = (float)(dy * dy + dx * dx) / 1800.0f;
                    #pragma unroll
                    for (int j = 0; j < 4; ++j) {
                        const int nx = xc + j + dx;
                        float kwv = 0.0f;
                        if ((unsigned)nx < 128u) {
                            const int m = j + dx + 1;
                            float d0 = rv0[m] - c0[j];
                            float d1 = rv1[m] - c1[j];
                            float d2 = rv2[m] - c2[j];
                            float ss = d0 * d0;
                            ss = ss + d1 * d1;
                            ss = ss + d2 * d2;
                            float color = (-ss) / 0.5f;
                            kwv = 3.0f * expf(color - sp);
                        }
                        kw[k][j] = kwv;
                    }
                }
            } else {
                #pragma unroll
                for (int dxi = 0; dxi < 3; ++dxi) {
                    kw[g * 3 + dxi][0] = 0.0f; kw[g * 3 + dxi][1] = 0.0f;
                    kw[g * 3 + dxi][2] = 0.0f; kw[g * 3 + dxi][3] = 0.0f;
                }
            }
        }
    }

    // ---- 5 sweeps, taps from registers -------------------------------------
    const float l45 = 0.7985076962177716f;  // -log(0.45f)
    const float l55 = 0.5978370007556204f;  // -log(0.55f)
    float* om = out + NM + (size_t)img * HW;
    int sA = 0, cnt = 0;
    #pragma unroll
    for (int s = 0; s < 5; ++s) {
        const int lo = (r0 - 4 + s < 0) ? 0 : r0 - 4 + s;
        const int hi = (r0 + 12 - s > 128) ? 128 : r0 + 12 - s;
        const bool last = (s == 4);
        const bool act = compute && (y >= lo) && (y < hi);
        if (act) {
            unsigned char rb[3][6];
            const uint32_t* sw = &stw[sA][0];
            #pragma unroll
            for (int r = 0; r < 3; ++r) {
                const int ry = y + r - 1;
                if ((unsigned)ry < 128u) {
                    const int base = (ry - w0) * 32 + (xc >> 2);
                    const uint32_t wm = (xc > 0) ? sw[base - 1] : 0u;
                    const uint32_t wc = sw[base];
                    const uint32_t wp = (xc < 124) ? sw[base + 1] : 0u;
                    rb[r][0] = wm >> 24;
                    rb[r][1] = wc & 0xff; rb[r][2] = (wc >> 8) & 0xff;
                    rb[r][3] = (wc >> 16) & 0xff; rb[r][4] = wc >> 24;
                    rb[r][5] = wp & 0xff;
                } else {
                    #pragma unroll
                    for (int m = 0; m < 6; ++m) rb[r][m] = 0;  // kw==0 there
                }
            }
            float a0[4] = {0.f, 0.f, 0.f, 0.f}, a1[4] = {0.f, 0.f, 0.f, 0.f};
            #pragma unroll
            for (int k = 0; k < 9; ++k) {
                #pragma unroll
                for (int j = 0; j < 4; ++j) {
                    const float kwv = kw[k][j];
                    const unsigned char sq = rb[k / 3][j + (k % 3)];
                    const float lx1 = (sq & 1) ? l55 : l45;
                    const float lx0 = (sq & 2) ? l55 : l45;
                    const float t1 = lx1 * kwv;   // mul then add (numpy order)
                    const float t0 = lx0 * kwv;
                    a1[j] = a1[j] + t1;
                    a0[j] = a0[j] + t0;
                }
            }
            // epilogue (proven exact sequence)
            uint32_t ow = 0;
            float mv[4];
            int c1 = 0;
            #pragma unroll
            for (int j = 0; j < 4; ++j) {
                const unsigned char sc = rb[1][j + 1];
                const float tval = (sc & 4) ? 1.0f : 0.0f;
                const float e1 = expf(-a1[j]);
                const float e0 = expf(-a0[j]);
                const float m1 = e1 * tval;
                const float f1 = m1 + 1e-6f;
                const float f0 = e0 + 1e-6f;
                const float den = f0 + f1;
                const float r1 = f1 / den;
                const float r0v = f0 / den;
                const int s1 = (r1 > 0.5f) ? 1 : 0;
                const int s0 = (r0v > 0.5f) ? 1 : 0;
                mv[j] = (float)s1;
                c1 += s1;
                ow |= (uint32_t)(s1 | (s0 << 1) | (sc & 4)) << (8 * j);
            }
            if (!last) {
                stw[sA ^ 1][tid] = ow;
            } else if (FIRST) {
                ((uint32_t*)(gdst2 + (size_t)img * HW))[y * 32 + (xc >> 2)] = ow;
            } else {
                *(float4*)(om + y * 128 + xc) = make_float4(mv[0], mv[1], mv[2], mv[3]);
                cnt = c1;
            }
        }
        __syncthreads();
        sA ^= 1;
    }

    // ---- phase B tail: counts + valid (proven ticket, 1024 blocks) ---------
    if (!FIRST) {
        int* cred = (int*)&fmL[0][0];
        cred[tid] = cnt;
        if (tid < 448) cred[576 + tid] = 0;   // pad to 1024
        __syncthreads();
        for (int off = 512; off > 0; off >>= 1) {
            if (tid < off) cred[tid] += cred[tid + off];
            __syncthreads();
        }
        int* flag = (int*)&stw[0][0];
        if (tid == 0) {
            atomicAdd(&counters[img], cred[0]);
            __threadfence();
            int old = atomicAdd(&counters[NI], 1);
            flag[0] = (old == 1023) ? 1 : 0;
        }
        __syncthreads();
        if (flag[0] && tid < NI) {
            int c = atomicAdd(&counters[tid], 0);
            // 16384*0.05 = 819.2, 16384*0.95 = 15564.8; counts are integers
            out[NM + (size_t)NI * HW + tid] = (c >= 820 && c <= 15564) ? 1.0f : 0.0f;
        }
    }
}

extern "C" void kernel_launch(void* const* d_in, const int* in_sizes, int n_in,
                              void* d_out, int out_size, void* d_ws, size_t ws_size,
                              hipStream_t stream) {
    const float* seg = (const float*)d_in[0];
    const float* cate_scores = (const float*)d_in[1];
    const float* feat = (const float*)d_in[2];
    const float* x = (const float*)d_in[3];
    const float* targets = (const float*)d_in[4];
    const int* labels = (const int*)d_in[5];
    float* out = (float*)d_out;
    char* ws = (char*)d_ws;

    unsigned char* state = (unsigned char*)(ws + OFF_STATE);
    unsigned char* state2 = (unsigned char*)(ws + OFF_STATE2);
    unsigned long long* packed = (unsigned long long*)(ws + OFF_PACKED);
    float* diouT = (float*)(ws + OFF_DIOUT);
    float* compm = (float*)(ws + OFF_COMPM);
    int* counters = (int*)(ws + OFF_CNT);

    setup_kernel<<<512, 256, 0, stream>>>(seg, x, targets, state, packed, counters);
    diou_compm_kernel<<<NM, 256, 0, stream>>>(packed, labels, diouT, compm);
    crf5_kernel<true><<<1024, 576, 0, stream>>>(feat, cate_scores, diouT, compm,
                                                state, state2, out, counters);
    crf5_kernel<false><<<1024, 576, 0, stream>>>(feat, cate_scores, diouT, compm,
                                                 state2, nullptr, out, counters);
}